// Round 2
// baseline (11942.129 us; speedup 1.0000x reference)
//
#include <hip/hip_runtime.h>

#define TSTEPS 784
#define BATCH  256
#define HDIM   512
#define NCLS   10

typedef __bf16 bf16x8 __attribute__((ext_vector_type(8)));
typedef float  f32x4  __attribute__((ext_vector_type(4)));
typedef unsigned short ushort8 __attribute__((ext_vector_type(8)));

static __device__ __forceinline__ unsigned short f2bf(float f) {
  unsigned u = __builtin_bit_cast(unsigned, f);
  u += 0x7fffu + ((u >> 16) & 1u);
  return (unsigned short)(u >> 16);
}
static __device__ __forceinline__ float bf2f(unsigned short s) {
  unsigned u = ((unsigned)s) << 16;
  return __builtin_bit_cast(float, u);
}

// ---------------- xp[t][b] = inputs[b][perm[t]] ----------------
// perm arrives as int32: the harness converts int64 inputs to int (per contract).
__global__ __launch_bounds__(256) void gather_xp(const float* __restrict__ in,
                                                 const int* __restrict__ perm,
                                                 float* __restrict__ xp) {
  int t = blockIdx.x;
  int b = threadIdx.x;
  int p = perm[t];
  // defensive clamp: a bad index becomes a wrong (diagnosable) value, not a GPU fault
  p = (p < 0) ? 0 : (p >= TSTEPS ? TSTEPS - 1 : p);
  xp[t * BATCH + b] = in[b * TSTEPS + p];
}

// ---------------- X = (triu(W,1) - triu(W,1)^T) / 32 ----------------
__global__ __launch_bounds__(256) void build_X(const float* __restrict__ W,
                                               float* __restrict__ X) {
  int idx = blockIdx.x * 256 + threadIdx.x;
  int i = idx >> 9, j = idx & 511;
  float v = 0.f;
  if (j > i) v = W[i * HDIM + j];
  else if (i > j) v = -W[j * HDIM + i];
  X[idx] = v * 0.03125f;
}

// ---------------- P = coef*X + I ----------------
__global__ __launch_bounds__(256) void axpyI(float* __restrict__ P,
                                             const float* __restrict__ X, float coef) {
  int idx = blockIdx.x * 256 + threadIdx.x;
  int i = idx >> 9, j = idx & 511;
  P[idx] = coef * X[idx] + ((i == j) ? 1.f : 0.f);
}

// ---------------- C = alpha*A*B (+I), 512^3 fp32, 64x64 tile ----------------
__global__ __launch_bounds__(256) void gemm512(float* __restrict__ C,
                                               const float* __restrict__ A,
                                               const float* __restrict__ B,
                                               float alpha, int addI) {
  __shared__ float As[16][68];
  __shared__ float Bs[16][68];
  const int tx = threadIdx.x, ty = threadIdx.y;
  const int tid = ty * 16 + tx;
  const int ib = blockIdx.y, jb = blockIdx.x;
  const int ra = tid >> 2, ca = (tid & 3) << 2;
  const int rb = tid >> 4, cb = (tid & 15) << 2;
  float acc[4][4] = {};
  for (int kt = 0; kt < HDIM / 16; ++kt) {
    f32x4 av = *(const f32x4*)(A + (ib * 64 + ra) * HDIM + kt * 16 + ca);
    f32x4 bv = *(const f32x4*)(B + (kt * 16 + rb) * HDIM + jb * 64 + cb);
    __syncthreads();
    As[ca + 0][ra] = av[0];
    As[ca + 1][ra] = av[1];
    As[ca + 2][ra] = av[2];
    As[ca + 3][ra] = av[3];
    *(f32x4*)&Bs[rb][cb] = bv;
    __syncthreads();
#pragma unroll
    for (int kk = 0; kk < 16; ++kk) {
      f32x4 a4 = *(const f32x4*)&As[kk][ty << 2];
      f32x4 b4 = *(const f32x4*)&Bs[kk][tx << 2];
#pragma unroll
      for (int u = 0; u < 4; ++u)
#pragma unroll
        for (int v = 0; v < 4; ++v) acc[u][v] = fmaf(a4[u], b4[v], acc[u][v]);
    }
  }
#pragma unroll
  for (int u = 0; u < 4; ++u)
#pragma unroll
    for (int v = 0; v < 4; ++v) {
      int r = ib * 64 + (ty << 2) + u, c = jb * 64 + (tx << 2) + v;
      float val = alpha * acc[u][v];
      if (addI && r == c) val += 1.f;
      C[r * HDIM + c] = val;
    }
}

// ---------------- grid barrier (generation-based, agent scope) ----------------
__device__ __forceinline__ void grid_barrier(unsigned* bar, int nwg) {
  __syncthreads();
  if (threadIdx.x == 0) {
    __threadfence();  // release: h writes drain past per-XCD L2
    unsigned g = __hip_atomic_load(bar + 1, __ATOMIC_ACQUIRE, __HIP_MEMORY_SCOPE_AGENT);
    unsigned arr = __hip_atomic_fetch_add(bar, 1u, __ATOMIC_ACQ_REL, __HIP_MEMORY_SCOPE_AGENT);
    if (arr == (unsigned)(nwg - 1)) {
      __hip_atomic_store(bar, 0u, __ATOMIC_RELAXED, __HIP_MEMORY_SCOPE_AGENT);
      __hip_atomic_store(bar + 1, g + 1u, __ATOMIC_RELEASE, __HIP_MEMORY_SCOPE_AGENT);
    } else {
      int spin = 0;
      while (__hip_atomic_load(bar + 1, __ATOMIC_RELAXED, __HIP_MEMORY_SCOPE_AGENT) == g) {
        __builtin_amdgcn_s_sleep(1);
        if (++spin > (1 << 20)) break;  // anti-hang valve: wrong answer beats a dead session
      }
    }
    __threadfence();  // acquire: invalidate caches before reading peers' h
  }
  __syncthreads();
}

// ---------------- persistent RNN scan ----------------
// 128 WGs x 256 thr. wave (wg>>4)*4+w owns cols [g_cw*16, g_cw*16+16), batch tile g_b = wg&15.
// Borth held register-resident as bf16 hi/lo MFMA B-fragments (full K=512).
// h ping-pongs in global as bf16 hi/lo planes -> A-path is pure loads, no per-step converts.
__global__ __launch_bounds__(256, 1) void rnn_main(
    const float* __restrict__ xp, const float* __restrict__ Borth,
    const float* __restrict__ W_in, const float* __restrict__ b_mod,
    const float* __restrict__ W_lin, const float* __restrict__ b_lin,
    unsigned short* __restrict__ h0hi, unsigned short* __restrict__ h0lo,
    unsigned short* __restrict__ h1hi, unsigned short* __restrict__ h1lo,
    unsigned* __restrict__ bar, float* __restrict__ out) {
  const int wg = blockIdx.x;
  const int g_b = wg & 15;
  const int tid = threadIdx.x;
  const int wave = tid >> 6;
  const int lane = tid & 63;
  const int quad = lane >> 4;
  const int l16 = lane & 15;
  const int g_cw = ((wg >> 4) << 2) + wave;  // 0..31
  const int colg = (g_cw << 4) + l16;        // this lane's output column
  const int rowA = (g_b << 4) + l16;         // this lane's A row

  // B fragments: B[k][n], lane element j <-> k = ki*32 + quad*8 + j, n = colg
  bf16x8 Bhi[16], Blo[16];
#pragma unroll
  for (int ki = 0; ki < 16; ++ki) {
#pragma unroll
    for (int j = 0; j < 8; ++j) {
      int k = (ki << 5) + (quad << 3) + j;
      float v = Borth[k * HDIM + colg];
      unsigned short hb = f2bf(v);
      Bhi[ki][j] = __builtin_bit_cast(__bf16, hb);
      Blo[ki][j] = __builtin_bit_cast(__bf16, f2bf(v - bf2f(hb)));
    }
  }
  const float win = W_in[colg];
  const float bm = b_mod[colg];
  const int nwg = gridDim.x;

  for (int t = 0; t < TSTEPS; ++t) {
    const unsigned short* __restrict__ chi = (t & 1) ? h1hi : h0hi;
    const unsigned short* __restrict__ clo = (t & 1) ? h1lo : h0lo;
    unsigned short* __restrict__ nhi = (t & 1) ? h0hi : h1hi;
    unsigned short* __restrict__ nlo = (t & 1) ? h0lo : h1lo;
    f32x4 a_hh = {0.f, 0.f, 0.f, 0.f};
    f32x4 a_lh = {0.f, 0.f, 0.f, 0.f};
    f32x4 a_hl = {0.f, 0.f, 0.f, 0.f};
    const int abase = rowA * HDIM + (quad << 3);
#pragma unroll
    for (int ki = 0; ki < 16; ++ki) {
      bf16x8 ah = __builtin_bit_cast(bf16x8, *(const ushort8*)(chi + abase + (ki << 5)));
      bf16x8 al = __builtin_bit_cast(bf16x8, *(const ushort8*)(clo + abase + (ki << 5)));
      a_hh = __builtin_amdgcn_mfma_f32_16x16x32_bf16(ah, Bhi[ki], a_hh, 0, 0, 0);
      a_lh = __builtin_amdgcn_mfma_f32_16x16x32_bf16(al, Bhi[ki], a_lh, 0, 0, 0);
      a_hl = __builtin_amdgcn_mfma_f32_16x16x32_bf16(ah, Blo[ki], a_hl, 0, 0, 0);
    }
    // C/D layout: row = quad*4 + r, col = l16 (verified m89/m91)
    const f32x4 xps = *(const f32x4*)(xp + t * BATCH + (g_b << 4) + (quad << 2));
#pragma unroll
    for (int r = 0; r < 4; ++r) {
      float pre = a_hh[r] + a_lh[r] + a_hl[r] + xps[r] * win;
      float mm = fmaxf(fabsf(pre) + bm, 0.f);
      float hv = (pre > 0.f) ? mm : ((pre < 0.f) ? -mm : 0.f);  // exact jnp.sign semantics
      int idx = ((g_b << 4) + (quad << 2) + r) * HDIM + colg;
      unsigned short hb = f2bf(hv);
      nhi[idx] = hb;
      nlo[idx] = f2bf(hv - bf2f(hb));
    }
    grid_barrier(bar, nwg);
  }

  // head: out = hT @ W_lin^T + b_lin ; final h lives in buffer 0 (t=783 odd writes h0)
  if ((wg >> 4) == 0) {
    int rowp = tid >> 4;
    int cls = tid & 15;
    if (cls < NCLS) {
      int grow = (g_b << 4) + rowp;
      const unsigned short* hih = h0hi + grow * HDIM;
      const unsigned short* hil = h0lo + grow * HDIM;
      const float* wl = W_lin + cls * HDIM;
      float s = b_lin[cls];
      for (int k = 0; k < HDIM; ++k) s = fmaf(bf2f(hih[k]) + bf2f(hil[k]), wl[k], s);
      out[grow * NCLS + cls] = s;
    }
  }
}

extern "C" void kernel_launch(void* const* d_in, const int* in_sizes, int n_in,
                              void* d_out, int out_size, void* d_ws, size_t ws_size,
                              hipStream_t stream) {
  const float* inputs = (const float*)d_in[0];  // 256x784
  const int* perm = (const int*)d_in[1];        // 784 (int64 -> int32 by harness)
  const float* W_skew = (const float*)d_in[2];  // 512x512
  const float* W_in = (const float*)d_in[3];    // 512
  const float* b_mod = (const float*)d_in[4];   // 512
  const float* W_lin = (const float*)d_in[5];   // 10x512
  const float* b_lin = (const float*)d_in[6];   // 10
  float* out = (float*)d_out;

  char* ws = (char*)d_ws;
  unsigned* bar = (unsigned*)ws;  // 256 B reserved
  unsigned short* h0hi = (unsigned short*)(ws + 256);
  unsigned short* h0lo = h0hi + BATCH * HDIM;
  unsigned short* h1hi = h0lo + BATCH * HDIM;
  unsigned short* h1lo = h1hi + BATCH * HDIM;
  float* xp = (float*)(h1lo + BATCH * HDIM);
  float* X = xp + TSTEPS * BATCH;
  float* P = X + HDIM * HDIM;
  float* Q = P + HDIM * HDIM;
  // total ws use ~4.9 MB

  hipMemsetAsync(bar, 0, 256, stream);
  hipMemsetAsync(h0hi, 0, (size_t)BATCH * HDIM * 2 * sizeof(unsigned short), stream);  // h0 hi+lo

  gather_xp<<<TSTEPS, 256, 0, stream>>>(inputs, perm, xp);
  build_X<<<(HDIM * HDIM) / 256, 256, 0, stream>>>(W_skew, X);

  // expm(A) = (T6(A/32))^(2^5), Horner: T = I + X(I + X/2(I + X/3(I + X/4(I + X/5(I + X/6)))))
  axpyI<<<(HDIM * HDIM) / 256, 256, 0, stream>>>(P, X, 1.f / 6.f);
  float* a = P;
  float* b = Q;
  for (int k = 5; k >= 1; --k) {
    gemm512<<<dim3(8, 8), dim3(16, 16), 0, stream>>>(b, X, a, 1.f / (float)k, 1);
    float* tmp = a; a = b; b = tmp;
  }
  for (int i = 0; i < 5; ++i) {
    gemm512<<<dim3(8, 8), dim3(16, 16), 0, stream>>>(b, a, a, 1.f, 0);
    float* tmp = a; a = b; b = tmp;
  }

  rnn_main<<<128, 256, 0, stream>>>(xp, a, W_in, b_mod, W_lin, b_lin,
                                    h0hi, h0lo, h1hi, h1lo, bar, out);
  (void)in_sizes; (void)n_in; (void)out_size; (void)ws_size;
}

// Round 3
// 7000.821 us; speedup vs baseline: 1.7058x; 1.7058x over previous
//
#include <hip/hip_runtime.h>

#define TSTEPS 784
#define BATCH  256
#define HDIM   512
#define NCLS   10
#define NGRP   16   // independent batch groups (16 rows each)
#define WGPG   16   // workgroups per group (16 col-groups of 32 cols)

typedef __bf16 bf16x8 __attribute__((ext_vector_type(8)));
typedef float  f32x4  __attribute__((ext_vector_type(4)));
typedef unsigned uint4v __attribute__((ext_vector_type(4)));

static __device__ __forceinline__ unsigned short f2bf(float f) {
  unsigned u = __builtin_bit_cast(unsigned, f);
  u += 0x7fffu + ((u >> 16) & 1u);
  return (unsigned short)(u >> 16);
}
static __device__ __forceinline__ float bf2f(unsigned s) {
  unsigned u = s << 16;
  return __builtin_bit_cast(float, u);
}

// ---------------- xp[t][b] = inputs[b][perm[t]] ----------------
__global__ __launch_bounds__(256) void gather_xp(const float* __restrict__ in,
                                                 const int* __restrict__ perm,
                                                 float* __restrict__ xp) {
  int t = blockIdx.x;
  int b = threadIdx.x;
  int p = perm[t];
  p = (p < 0) ? 0 : (p >= TSTEPS ? TSTEPS - 1 : p);
  xp[t * BATCH + b] = in[b * TSTEPS + p];
}

// ---------------- X = (triu(W,1) - triu(W,1)^T) / 32 ----------------
__global__ __launch_bounds__(256) void build_X(const float* __restrict__ W,
                                               float* __restrict__ X) {
  int idx = blockIdx.x * 256 + threadIdx.x;
  int i = idx >> 9, j = idx & 511;
  float v = 0.f;
  if (j > i) v = W[i * HDIM + j];
  else if (i > j) v = -W[j * HDIM + i];
  X[idx] = v * 0.03125f;
}

// ---------------- P = coef*X + I ----------------
__global__ __launch_bounds__(256) void axpyI(float* __restrict__ P,
                                             const float* __restrict__ X, float coef) {
  int idx = blockIdx.x * 256 + threadIdx.x;
  int i = idx >> 9, j = idx & 511;
  P[idx] = coef * X[idx] + ((i == j) ? 1.f : 0.f);
}

// ---------------- C = alpha*A*B (+I), 512^3 fp32, 64x64 tile ----------------
__global__ __launch_bounds__(256) void gemm512(float* __restrict__ C,
                                               const float* __restrict__ A,
                                               const float* __restrict__ B,
                                               float alpha, int addI) {
  __shared__ float As[16][68];
  __shared__ float Bs[16][68];
  const int tx = threadIdx.x, ty = threadIdx.y;
  const int tid = ty * 16 + tx;
  const int ib = blockIdx.y, jb = blockIdx.x;
  const int ra = tid >> 2, ca = (tid & 3) << 2;
  const int rb = tid >> 4, cb = (tid & 15) << 2;
  float acc[4][4] = {};
  for (int kt = 0; kt < HDIM / 16; ++kt) {
    f32x4 av = *(const f32x4*)(A + (ib * 64 + ra) * HDIM + kt * 16 + ca);
    f32x4 bv = *(const f32x4*)(B + (kt * 16 + rb) * HDIM + jb * 64 + cb);
    __syncthreads();
    As[ca + 0][ra] = av[0];
    As[ca + 1][ra] = av[1];
    As[ca + 2][ra] = av[2];
    As[ca + 3][ra] = av[3];
    *(f32x4*)&Bs[rb][cb] = bv;
    __syncthreads();
#pragma unroll
    for (int kk = 0; kk < 16; ++kk) {
      f32x4 a4 = *(const f32x4*)&As[kk][ty << 2];
      f32x4 b4 = *(const f32x4*)&Bs[kk][tx << 2];
#pragma unroll
      for (int u = 0; u < 4; ++u)
#pragma unroll
        for (int v = 0; v < 4; ++v) acc[u][v] = fmaf(a4[u], b4[v], acc[u][v]);
    }
  }
#pragma unroll
  for (int u = 0; u < 4; ++u)
#pragma unroll
    for (int v = 0; v < 4; ++v) {
      int r = ib * 64 + (ty << 2) + u, c = jb * 64 + (tx << 2) + v;
      float val = alpha * acc[u][v];
      if (addI && r == c) val += 1.f;
      C[r * HDIM + c] = val;
    }
}

// ---------------- persistent RNN scan, group-local barriers ----------------
// 256 WGs x 128 thr (2 waves). wg = cg*16 + gb is WRONG order -- we use
// gb = wg & 15 (batch tile), cg = wg >> 4 (col group). Wave owns 16 cols.
// h lives in global as ONE packed dword per element: (bf16_hi << 16) | bf16_lo.
// All h traffic is agent-scope relaxed atomics => global_load/store_dword sc1:
// write-through to coherent L3, reads bypass (possibly stale) per-XCD L2.
// NO threadfence => no buffer_wbl2 / buffer_inv per step.
// Barrier: per-group monotonic counter; arrive after __syncthreads (which
// drains vmcnt => our sc1 stores are at the coherence point).
__global__ __launch_bounds__(128, 1) void rnn_main(
    const float* __restrict__ xp, const float* __restrict__ Borth,
    const float* __restrict__ W_in, const float* __restrict__ b_mod,
    const float* __restrict__ W_lin, const float* __restrict__ b_lin,
    unsigned* __restrict__ h0p, unsigned* __restrict__ h1p,
    unsigned* __restrict__ counters, float* __restrict__ out) {
  const int wg = blockIdx.x;
  const int gb = wg & 15;   // batch group: rows [gb*16, gb*16+16)
  const int cg = wg >> 4;   // col group:   cols [cg*32, cg*32+32)
  const int tid = threadIdx.x;
  const int wave = tid >> 6;
  const int lane = tid & 63;
  const int quad = lane >> 4;
  const int l16 = lane & 15;
  const int colg = ((cg * 2 + wave) << 4) + l16;  // this lane's output column
  const int rowA = (gb << 4) + l16;               // this lane's A row
  unsigned* cnt = counters + gb * 32;             // 128 B apart per group

  // B fragments, register-resident: B[k][n], lane elem j <-> k = ki*32+quad*8+j, n = colg
  bf16x8 Bhi[16], Blo[16];
#pragma unroll
  for (int ki = 0; ki < 16; ++ki) {
#pragma unroll
    for (int j = 0; j < 8; ++j) {
      int k = (ki << 5) + (quad << 3) + j;
      float v = Borth[k * HDIM + colg];
      unsigned short hb = f2bf(v);
      Bhi[ki][j] = __builtin_bit_cast(__bf16, hb);
      Blo[ki][j] = __builtin_bit_cast(__bf16, f2bf((unsigned)f2bf(v - bf2f(hb)) << 0) == 0.f
                                                 ? f2bf(v - bf2f(hb))
                                                 : f2bf(v - bf2f(hb)));
    }
  }
  // (the ternary above is a no-op; kept simple:)
#pragma unroll
  for (int ki = 0; ki < 16; ++ki) {
#pragma unroll
    for (int j = 0; j < 8; ++j) {
      int k = (ki << 5) + (quad << 3) + j;
      float v = Borth[k * HDIM + colg];
      unsigned short hb = f2bf(v);
      unsigned short lb = f2bf(v - bf2f(hb));
      Bhi[ki][j] = __builtin_bit_cast(__bf16, hb);
      Blo[ki][j] = __builtin_bit_cast(__bf16, lb);
    }
  }
  const float win = W_in[colg];
  const float bm = b_mod[colg];

  for (int t = 0; t < TSTEPS; ++t) {
    const unsigned* __restrict__ cur = (t & 1) ? h1p : h0p;
    unsigned* __restrict__ nxt = (t & 1) ? h0p : h1p;

    // ---- issue ALL 128 A-loads up front (program-order atomics pipeline) ----
    unsigned d[16][8];
    const unsigned* hb = cur + rowA * HDIM + (quad << 3);
#pragma unroll
    for (int ki = 0; ki < 16; ++ki)
#pragma unroll
      for (int j = 0; j < 8; ++j)
        d[ki][j] = __hip_atomic_load(hb + (ki << 5) + j, __ATOMIC_RELAXED,
                                     __HIP_MEMORY_SCOPE_AGENT);

    f32x4 a_hh = {0.f, 0.f, 0.f, 0.f};
    f32x4 a_lh = {0.f, 0.f, 0.f, 0.f};
    f32x4 a_hl = {0.f, 0.f, 0.f, 0.f};
#pragma unroll
    for (int ki = 0; ki < 16; ++ki) {
      // unpack packed dwords -> hi-plane / lo-plane bf16x8 via v_perm
      uint4v vh, vl;
#pragma unroll
      for (int p = 0; p < 4; ++p) {
        vh[p] = __builtin_amdgcn_perm(d[ki][2 * p + 1], d[ki][2 * p], 0x07060302u);
        vl[p] = __builtin_amdgcn_perm(d[ki][2 * p + 1], d[ki][2 * p], 0x05040100u);
      }
      bf16x8 ah = __builtin_bit_cast(bf16x8, vh);
      bf16x8 al = __builtin_bit_cast(bf16x8, vl);
      a_hh = __builtin_amdgcn_mfma_f32_16x16x32_bf16(ah, Bhi[ki], a_hh, 0, 0, 0);
      a_lh = __builtin_amdgcn_mfma_f32_16x16x32_bf16(al, Bhi[ki], a_lh, 0, 0, 0);
      a_hl = __builtin_amdgcn_mfma_f32_16x16x32_bf16(ah, Blo[ki], a_hl, 0, 0, 0);
    }

    // C/D layout: row = quad*4 + r, col = l16
    const f32x4 xps = *(const f32x4*)(xp + t * BATCH + (gb << 4) + (quad << 2));
#pragma unroll
    for (int r = 0; r < 4; ++r) {
      float pre = a_hh[r] + a_lh[r] + a_hl[r] + xps[r] * win;
      float mm = fmaxf(fabsf(pre) + bm, 0.f);
      float hv = (pre > 0.f) ? mm : ((pre < 0.f) ? -mm : 0.f);
      int idx = ((gb << 4) + (quad << 2) + r) * HDIM + colg;
      unsigned short hbv = f2bf(hv);
      unsigned short lbv = f2bf(hv - bf2f(hbv));
      unsigned pk = ((unsigned)hbv << 16) | (unsigned)lbv;
      __hip_atomic_store(nxt + idx, pk, __ATOMIC_RELAXED, __HIP_MEMORY_SCOPE_AGENT);
    }

    // ---- group barrier ----
    asm volatile("s_waitcnt vmcnt(0)" ::: "memory");  // belt & braces: drain sc1 stores
    __syncthreads();
    if (tid == 0) {
      __hip_atomic_fetch_add(cnt, 1u, __ATOMIC_RELAXED, __HIP_MEMORY_SCOPE_AGENT);
      const unsigned target = (unsigned)(WGPG) * (unsigned)(t + 1);
      int spin = 0;
      while (__hip_atomic_load(cnt, __ATOMIC_RELAXED, __HIP_MEMORY_SCOPE_AGENT) < target) {
        __builtin_amdgcn_s_sleep(1);
        if (++spin > (1 << 22)) break;  // anti-hang valve
      }
    }
    __atomic_signal_fence(__ATOMIC_SEQ_CST);
    __syncthreads();
  }

  // ---- head: out = hT @ W_lin^T + b_lin ; final h in h0p (t=783 odd -> writes h0) ----
  if (cg == 0) {
    const unsigned* hf = h0p + (gb << 4) * HDIM;
    int row = tid >> 3;  // 0..15
    int c0 = tid & 7;
    for (int cls = c0; cls < NCLS; cls += 8) {
      float s = b_lin[cls];
      const float* wl = W_lin + cls * HDIM;
      for (int k = 0; k < HDIM; ++k) {
        unsigned p = __hip_atomic_load(hf + row * HDIM + k, __ATOMIC_RELAXED,
                                       __HIP_MEMORY_SCOPE_AGENT);
        float hvv = bf2f(p >> 16) + bf2f(p & 0xffffu);
        s = fmaf(hvv, wl[k], s);
      }
      out[((gb << 4) + row) * NCLS + cls] = s;
    }
  }
}

extern "C" void kernel_launch(void* const* d_in, const int* in_sizes, int n_in,
                              void* d_out, int out_size, void* d_ws, size_t ws_size,
                              hipStream_t stream) {
  const float* inputs = (const float*)d_in[0];  // 256x784
  const int* perm = (const int*)d_in[1];        // 784 (int64 -> int32 by harness)
  const float* W_skew = (const float*)d_in[2];  // 512x512
  const float* W_in = (const float*)d_in[3];    // 512
  const float* b_mod = (const float*)d_in[4];   // 512
  const float* W_lin = (const float*)d_in[5];   // 10x512
  const float* b_lin = (const float*)d_in[6];   // 10
  float* out = (float*)d_out;

  char* ws = (char*)d_ws;
  unsigned* counters = (unsigned*)ws;                    // 4 KB reserved
  unsigned* h0p = (unsigned*)(ws + 4096);                // 256*512 dwords
  unsigned* h1p = h0p + BATCH * HDIM;
  float* xp = (float*)(h1p + BATCH * HDIM);
  float* X = xp + TSTEPS * BATCH;
  float* P = X + HDIM * HDIM;
  float* Q = P + HDIM * HDIM;
  // total ws use ~5.2 MB

  hipMemsetAsync(counters, 0, 4096, stream);
  hipMemsetAsync(h0p, 0, (size_t)BATCH * HDIM * sizeof(unsigned), stream);

  gather_xp<<<TSTEPS, 256, 0, stream>>>(inputs, perm, xp);
  build_X<<<(HDIM * HDIM) / 256, 256, 0, stream>>>(W_skew, X);

  // expm(A) = (T6(A/32))^(2^5)
  axpyI<<<(HDIM * HDIM) / 256, 256, 0, stream>>>(P, X, 1.f / 6.f);
  float* a = P;
  float* b = Q;
  for (int k = 5; k >= 1; --k) {
    gemm512<<<dim3(8, 8), dim3(16, 16), 0, stream>>>(b, X, a, 1.f / (float)k, 1);
    float* tmp = a; a = b; b = tmp;
  }
  for (int i = 0; i < 5; ++i) {
    gemm512<<<dim3(8, 8), dim3(16, 16), 0, stream>>>(b, a, a, 1.f, 0);
    float* tmp = a; a = b; b = tmp;
  }

  rnn_main<<<NGRP * WGPG, 128, 0, stream>>>(xp, a, W_in, b_mod, W_lin, b_lin,
                                            h0p, h1p, counters, out);
  (void)in_sizes; (void)n_in; (void)out_size; (void)ws_size;
}

// Round 5
// 3391.286 us; speedup vs baseline: 3.5214x; 2.0644x over previous
//
#include <hip/hip_runtime.h>

#define TSTEPS 784
#define BATCH  256
#define HDIM   512
#define NCLS   10
#define NGRP   16   // independent batch groups (16 rows each)
#define WGPG   8    // workgroups per group (8 col-blocks of 64 cols)

typedef __bf16 bf16x8 __attribute__((ext_vector_type(8)));
typedef float  f32x4  __attribute__((ext_vector_type(4)));
typedef unsigned uint4v __attribute__((ext_vector_type(4)));

static __device__ __forceinline__ unsigned short f2bf(float f) {
  unsigned u = __builtin_bit_cast(unsigned, f);
  u += 0x7fffu + ((u >> 16) & 1u);
  return (unsigned short)(u >> 16);
}
static __device__ __forceinline__ float bf2f(unsigned s) {
  unsigned u = s << 16;
  return __builtin_bit_cast(float, u);
}

// ---------------- xp[t][b] = inputs[b][perm[t]] ----------------
__global__ __launch_bounds__(256) void gather_xp(const float* __restrict__ in,
                                                 const int* __restrict__ perm,
                                                 float* __restrict__ xp) {
  int t = blockIdx.x;
  int b = threadIdx.x;
  int p = perm[t];
  p = (p < 0) ? 0 : (p >= TSTEPS ? TSTEPS - 1 : p);
  xp[t * BATCH + b] = in[b * TSTEPS + p];
}

// ---------------- X = (triu(W,1) - triu(W,1)^T) / 32 ----------------
__global__ __launch_bounds__(256) void build_X(const float* __restrict__ W,
                                               float* __restrict__ X) {
  int idx = blockIdx.x * 256 + threadIdx.x;
  int i = idx >> 9, j = idx & 511;
  float v = 0.f;
  if (j > i) v = W[i * HDIM + j];
  else if (i > j) v = -W[j * HDIM + i];
  X[idx] = v * 0.03125f;
}

// ---------------- P = coef*X + I ----------------
__global__ __launch_bounds__(256) void axpyI(float* __restrict__ P,
                                             const float* __restrict__ X, float coef) {
  int idx = blockIdx.x * 256 + threadIdx.x;
  int i = idx >> 9, j = idx & 511;
  P[idx] = coef * X[idx] + ((i == j) ? 1.f : 0.f);
}

// ---------------- C = alpha*A*B (+I), 512^3 fp32, 64x64 tile ----------------
__global__ __launch_bounds__(256) void gemm512(float* __restrict__ C,
                                               const float* __restrict__ A,
                                               const float* __restrict__ B,
                                               float alpha, int addI) {
  __shared__ float As[16][68];
  __shared__ float Bs[16][68];
  const int tx = threadIdx.x, ty = threadIdx.y;
  const int tid = ty * 16 + tx;
  const int ib = blockIdx.y, jb = blockIdx.x;
  const int ra = tid >> 2, ca = (tid & 3) << 2;
  const int rb = tid >> 4, cb = (tid & 15) << 2;
  float acc[4][4] = {};
  for (int kt = 0; kt < HDIM / 16; ++kt) {
    f32x4 av = *(const f32x4*)(A + (ib * 64 + ra) * HDIM + kt * 16 + ca);
    f32x4 bv = *(const f32x4*)(B + (kt * 16 + rb) * HDIM + jb * 64 + cb);
    __syncthreads();
    As[ca + 0][ra] = av[0];
    As[ca + 1][ra] = av[1];
    As[ca + 2][ra] = av[2];
    As[ca + 3][ra] = av[3];
    *(f32x4*)&Bs[rb][cb] = bv;
    __syncthreads();
#pragma unroll
    for (int kk = 0; kk < 16; ++kk) {
      f32x4 a4 = *(const f32x4*)&As[kk][ty << 2];
      f32x4 b4 = *(const f32x4*)&Bs[kk][tx << 2];
#pragma unroll
      for (int u = 0; u < 4; ++u)
#pragma unroll
        for (int v = 0; v < 4; ++v) acc[u][v] = fmaf(a4[u], b4[v], acc[u][v]);
    }
  }
#pragma unroll
  for (int u = 0; u < 4; ++u)
#pragma unroll
    for (int v = 0; v < 4; ++v) {
      int r = ib * 64 + (ty << 2) + u, c = jb * 64 + (tx << 2) + v;
      float val = alpha * acc[u][v];
      if (addI && r == c) val += 1.f;
      C[r * HDIM + c] = val;
    }
}

// ---------------- persistent RNN scan ----------------
// 128 WGs x 256 thr (4 waves). gb = wg&15 (batch group), cg = wg>>4 in 0..7
// (col block of 64). Wave `wave` owns cols cg*64 + wave*16 + [0,16).
// h in global ROW-MAJOR packed dwords (hi<<16|lo)  [R3-proven layout+stores].
// Per step: cooperative stage of the group's 16x512 A-tile (8192 contiguous
// dwords) into LDS: each lane does 16 pipelined 8B sc1 atomic loads (one
// batch, 32 VGPRs) + identity ds_write_b64; syncthreads; fragment
// ds_read_b128 (2-way bank alias only = free); split-bf16 MFMA; sc1 stores;
// flag barrier (8 flags/group, no RMW).
__global__ __launch_bounds__(256, 1) void rnn_main(
    const float* __restrict__ xp, const float* __restrict__ Borth,
    const float* __restrict__ W_in, const float* __restrict__ b_mod,
    const float* __restrict__ W_lin, const float* __restrict__ b_lin,
    unsigned* __restrict__ h0p, unsigned* __restrict__ h1p,
    unsigned* __restrict__ flags, float* __restrict__ out) {
  __shared__ unsigned tileA[16 * HDIM];  // 32 KB, row-major [row16][k512]

  const int wg = blockIdx.x;
  const int gb = wg & 15;   // batch group: rows [gb*16, gb*16+16)
  const int cg = wg >> 4;   // col block:   cols [cg*64, cg*64+64)
  const int tid = threadIdx.x;
  const int wave = tid >> 6;
  const int lane = tid & 63;
  const int quad = lane >> 4;
  const int l16 = lane & 15;
  const int colg = (cg << 6) + (wave << 4) + l16;  // this lane's output column

  // B fragments, register-resident: B[k][n], lane elem j <-> k = ki*32+quad*8+j, n = colg
  bf16x8 Bhi[16], Blo[16];
#pragma unroll
  for (int ki = 0; ki < 16; ++ki) {
#pragma unroll
    for (int j = 0; j < 8; ++j) {
      int k = (ki << 5) + (quad << 3) + j;
      float v = Borth[k * HDIM + colg];
      unsigned short hb = f2bf(v);
      unsigned short lb = f2bf(v - bf2f(hb));
      Bhi[ki][j] = __builtin_bit_cast(__bf16, hb);
      Blo[ki][j] = __builtin_bit_cast(__bf16, lb);
    }
  }
  const float win = W_in[colg];
  const float bm = b_mod[colg];

  unsigned* const gbase0 = h0p + (gb << 13);  // rows gb*16..: 8192 contiguous dwords
  unsigned* const gbase1 = h1p + (gb << 13);
  unsigned* const myflag = flags + ((gb << 3) + cg) * 32;  // 128 B apart
  unsigned* const gflags = flags + (gb << 3) * 32;
  unsigned long long* const tileQ = (unsigned long long*)tileA;

  for (int t = 0; t < TSTEPS; ++t) {
    const unsigned* __restrict__ cur = (t & 1) ? gbase1 : gbase0;
    unsigned* __restrict__ nxt = (t & 1) ? gbase0 : gbase1;

    // ---- cooperative stage: 4096 qwords; lane tid loads qword tid + 256*i ----
    unsigned long long q[16];
    const unsigned long long* curq = (const unsigned long long*)cur;
#pragma unroll
    for (int i = 0; i < 16; ++i)
      q[i] = __hip_atomic_load(curq + tid + (i << 8), __ATOMIC_RELAXED,
                               __HIP_MEMORY_SCOPE_AGENT);
#pragma unroll
    for (int i = 0; i < 16; ++i)
      tileQ[tid + (i << 8)] = q[i];  // identity copy: ds_write_b64, conflict-free
    __syncthreads();

    // ---- fragment reads + split-bf16 MFMA ----
    f32x4 a_hh = {0.f, 0.f, 0.f, 0.f};
    f32x4 a_lh = {0.f, 0.f, 0.f, 0.f};
    f32x4 a_hl = {0.f, 0.f, 0.f, 0.f};
#pragma unroll
    for (int ki = 0; ki < 16; ++ki) {
      const unsigned* lp = tileA + (l16 << 9) + (ki << 5) + (quad << 3);
      uint4v d0 = *(const uint4v*)lp;        // j = 0..3
      uint4v d1 = *(const uint4v*)(lp + 4);  // j = 4..7
      unsigned d[8] = {d0[0], d0[1], d0[2], d0[3], d1[0], d1[1], d1[2], d1[3]};
      uint4v vh, vl;
#pragma unroll
      for (int p = 0; p < 4; ++p) {
        vh[p] = __builtin_amdgcn_perm(d[2 * p + 1], d[2 * p], 0x07060302u);
        vl[p] = __builtin_amdgcn_perm(d[2 * p + 1], d[2 * p], 0x05040100u);
      }
      bf16x8 ah = __builtin_bit_cast(bf16x8, vh);
      bf16x8 al = __builtin_bit_cast(bf16x8, vl);
      a_hh = __builtin_amdgcn_mfma_f32_16x16x32_bf16(ah, Bhi[ki], a_hh, 0, 0, 0);
      a_lh = __builtin_amdgcn_mfma_f32_16x16x32_bf16(al, Bhi[ki], a_lh, 0, 0, 0);
      a_hl = __builtin_amdgcn_mfma_f32_16x16x32_bf16(ah, Blo[ki], a_hl, 0, 0, 0);
    }

    // C/D layout: row = quad*4 + r, col = l16  [R3-proven]
    const f32x4 xps = *(const f32x4*)(xp + t * BATCH + (gb << 4) + (quad << 2));
#pragma unroll
    for (int r = 0; r < 4; ++r) {
      float pre = a_hh[r] + a_lh[r] + a_hl[r] + xps[r] * win;
      float mm = fmaxf(fabsf(pre) + bm, 0.f);
      float hv = (pre > 0.f) ? mm : ((pre < 0.f) ? -mm : 0.f);
      int idx = (((quad << 2) + r) << 9) + colg;  // local row * 512 + col
      unsigned short hbv = f2bf(hv);
      unsigned short lbv = f2bf(hv - bf2f(hbv));
      unsigned pk = ((unsigned)hbv << 16) | (unsigned)lbv;
      __hip_atomic_store(nxt + idx, pk, __ATOMIC_RELAXED, __HIP_MEMORY_SCOPE_AGENT);
    }

    // ---- flag barrier (8 WGs per group) ----
    asm volatile("s_waitcnt vmcnt(0)" ::: "memory");  // h stores at coherence point
    __syncthreads();                                  // all 4 waves drained + done reading LDS
    if (tid == 0)
      __hip_atomic_store(myflag, (unsigned)(t + 1), __ATOMIC_RELAXED,
                         __HIP_MEMORY_SCOPE_AGENT);
    const unsigned target = (unsigned)(t + 1);
    int spin = 0;
    for (;;) {
      unsigned fl = __hip_atomic_load(gflags + (lane & 7) * 32, __ATOMIC_RELAXED,
                                      __HIP_MEMORY_SCOPE_AGENT);
      if (__ballot(fl >= target) == ~0ull) break;
      __builtin_amdgcn_s_sleep(1);
      if (++spin > (1 << 22)) break;  // anti-hang valve
    }
  }

  // ---- head: out = hT @ W_lin^T + b_lin ; final h in h0p (t=783 odd -> writes gbase0) ----
  if (cg == 0) {
    int row = tid >> 4;  // 0..15
    int cls = tid & 15;
    if (cls < NCLS) {
      const unsigned* hf = gbase0 + (row << 9);
      float s = b_lin[cls];
      const float* wl = W_lin + cls * HDIM;
      for (int k = 0; k < HDIM; ++k) {
        unsigned p = __hip_atomic_load(hf + k, __ATOMIC_RELAXED, __HIP_MEMORY_SCOPE_AGENT);
        float hvv = bf2f(p >> 16) + bf2f(p & 0xffffu);
        s = fmaf(hvv, wl[k], s);
      }
      out[((gb << 4) + row) * NCLS + cls] = s;
    }
  }
}

extern "C" void kernel_launch(void* const* d_in, const int* in_sizes, int n_in,
                              void* d_out, int out_size, void* d_ws, size_t ws_size,
                              hipStream_t stream) {
  const float* inputs = (const float*)d_in[0];  // 256x784
  const int* perm = (const int*)d_in[1];        // 784 (int64 -> int32 by harness)
  const float* W_skew = (const float*)d_in[2];  // 512x512
  const float* W_in = (const float*)d_in[3];    // 512
  const float* b_mod = (const float*)d_in[4];   // 512
  const float* W_lin = (const float*)d_in[5];   // 10x512
  const float* b_lin = (const float*)d_in[6];   // 10
  float* out = (float*)d_out;

  char* ws = (char*)d_ws;
  unsigned* flags = (unsigned*)ws;           // 128 WGs * 128B = 16KB (32KB reserved)
  unsigned* h0p = (unsigned*)(ws + 32768);   // 128K dwords = 512KB
  unsigned* h1p = h0p + BATCH * HDIM;
  float* xp = (float*)(h1p + BATCH * HDIM);
  float* X = xp + TSTEPS * BATCH;
  float* P = X + HDIM * HDIM;
  float* Q = P + HDIM * HDIM;
  // total ws use ~5.0 MB

  hipMemsetAsync(flags, 0, 32768, stream);
  hipMemsetAsync(h0p, 0, (size_t)BATCH * HDIM * sizeof(unsigned), stream);

  gather_xp<<<TSTEPS, 256, 0, stream>>>(inputs, perm, xp);
  build_X<<<(HDIM * HDIM) / 256, 256, 0, stream>>>(W_skew, X);

  // expm(A) = (T6(A/32))^(2^5)
  axpyI<<<(HDIM * HDIM) / 256, 256, 0, stream>>>(P, X, 1.f / 6.f);
  float* a = P;
  float* b = Q;
  for (int k = 5; k >= 1; --k) {
    gemm512<<<dim3(8, 8), dim3(16, 16), 0, stream>>>(b, X, a, 1.f / (float)k, 1);
    float* tmp = a; a = b; b = tmp;
  }
  for (int i = 0; i < 5; ++i) {
    gemm512<<<dim3(8, 8), dim3(16, 16), 0, stream>>>(b, a, a, 1.f, 0);
    float* tmp = a; a = b; b = tmp;
  }

  rnn_main<<<NGRP * WGPG, 256, 0, stream>>>(xp, a, W_in, b_mod, W_lin, b_lin,
                                            h0p, h1p, flags, out);
  (void)in_sizes; (void)n_in; (void)out_size; (void)ws_size;
}

// Round 6
// 2556.410 us; speedup vs baseline: 4.6714x; 1.3266x over previous
//
#include <hip/hip_runtime.h>

#define TSTEPS 784
#define BATCH  256
#define HDIM   512
#define NCLS   10
#define NGRP   16   // independent batch groups (16 rows each)
#define WGPG   8    // workgroups per group (8 col-blocks of 64 cols)

typedef __bf16 bf16x8 __attribute__((ext_vector_type(8)));
typedef float  f32x4  __attribute__((ext_vector_type(4)));
typedef unsigned uint4v __attribute__((ext_vector_type(4)));

static __device__ __forceinline__ unsigned short f2bf(float f) {
  unsigned u = __builtin_bit_cast(unsigned, f);
  u += 0x7fffu + ((u >> 16) & 1u);
  return (unsigned short)(u >> 16);
}
static __device__ __forceinline__ float bf2f(unsigned s) {
  unsigned u = s << 16;
  return __builtin_bit_cast(float, u);
}

// ---------------- xp[t][b] = inputs[b][perm[t]] ----------------
__global__ __launch_bounds__(256) void gather_xp(const float* __restrict__ in,
                                                 const int* __restrict__ perm,
                                                 float* __restrict__ xp) {
  int t = blockIdx.x;
  int b = threadIdx.x;
  int p = perm[t];
  p = (p < 0) ? 0 : (p >= TSTEPS ? TSTEPS - 1 : p);
  xp[t * BATCH + b] = in[b * TSTEPS + p];
}

// ---------------- X = (triu(W,1) - triu(W,1)^T) / 32 ----------------
__global__ __launch_bounds__(256) void build_X(const float* __restrict__ W,
                                               float* __restrict__ X) {
  int idx = blockIdx.x * 256 + threadIdx.x;
  int i = idx >> 9, j = idx & 511;
  float v = 0.f;
  if (j > i) v = W[i * HDIM + j];
  else if (i > j) v = -W[j * HDIM + i];
  X[idx] = v * 0.03125f;
}

// ---------------- P = coef*X + I ----------------
__global__ __launch_bounds__(256) void axpyI(float* __restrict__ P,
                                             const float* __restrict__ X, float coef) {
  int idx = blockIdx.x * 256 + threadIdx.x;
  int i = idx >> 9, j = idx & 511;
  P[idx] = coef * X[idx] + ((i == j) ? 1.f : 0.f);
}

// ---------------- C = alpha*A*B (+I), 512^3 fp32, 64x64 tile ----------------
__global__ __launch_bounds__(256) void gemm512(float* __restrict__ C,
                                               const float* __restrict__ A,
                                               const float* __restrict__ B,
                                               float alpha, int addI) {
  __shared__ float As[16][68];
  __shared__ float Bs[16][68];
  const int tx = threadIdx.x, ty = threadIdx.y;
  const int tid = ty * 16 + tx;
  const int ib = blockIdx.y, jb = blockIdx.x;
  const int ra = tid >> 2, ca = (tid & 3) << 2;
  const int rb = tid >> 4, cb = (tid & 15) << 2;
  float acc[4][4] = {};
  for (int kt = 0; kt < HDIM / 16; ++kt) {
    f32x4 av = *(const f32x4*)(A + (ib * 64 + ra) * HDIM + kt * 16 + ca);
    f32x4 bv = *(const f32x4*)(B + (kt * 16 + rb) * HDIM + jb * 64 + cb);
    __syncthreads();
    As[ca + 0][ra] = av[0];
    As[ca + 1][ra] = av[1];
    As[ca + 2][ra] = av[2];
    As[ca + 3][ra] = av[3];
    *(f32x4*)&Bs[rb][cb] = bv;
    __syncthreads();
#pragma unroll
    for (int kk = 0; kk < 16; ++kk) {
      f32x4 a4 = *(const f32x4*)&As[kk][ty << 2];
      f32x4 b4 = *(const f32x4*)&Bs[kk][tx << 2];
#pragma unroll
      for (int u = 0; u < 4; ++u)
#pragma unroll
        for (int v = 0; v < 4; ++v) acc[u][v] = fmaf(a4[u], b4[v], acc[u][v]);
    }
  }
#pragma unroll
  for (int u = 0; u < 4; ++u)
#pragma unroll
    for (int v = 0; v < 4; ++v) {
      int r = ib * 64 + (ty << 2) + u, c = jb * 64 + (tx << 2) + v;
      float val = alpha * acc[u][v];
      if (addI && r == c) val += 1.f;
      C[r * HDIM + c] = val;
    }
}

// ---------------- persistent RNN scan ----------------
// 128 WGs x 256 thr (4 waves). gb = wg&15 (batch group), cg = wg>>4 in 0..7.
// h in global ROW-MAJOR packed dwords (hi<<16|lo)  [R3-proven layout+stores].
// LDS tile is XOR-SWIZZLED: physical dword = (row<<9) | (col ^ ((row&7)<<2)).
// This spreads the fragment ds_read_b128 pattern (16 rows x same cols) evenly
// across all 32 banks (8 accesses/bank = wave64-b128 floor); R5's unswizzled
// layout had row-stride 512 = 0 mod 32 -> 16-way conflicts (3.6e8 counted).
__global__ __launch_bounds__(256, 1) void rnn_main(
    const float* __restrict__ xp, const float* __restrict__ Borth,
    const float* __restrict__ W_in, const float* __restrict__ b_mod,
    const float* __restrict__ W_lin, const float* __restrict__ b_lin,
    unsigned* __restrict__ h0p, unsigned* __restrict__ h1p,
    unsigned* __restrict__ flags, float* __restrict__ out) {
  __shared__ unsigned tileA[16 * HDIM];  // 32 KB, swizzled [row16][k512]

  const int wg = blockIdx.x;
  const int gb = wg & 15;   // batch group: rows [gb*16, gb*16+16)
  const int cg = wg >> 4;   // col block:   cols [cg*64, cg*64+64)
  const int tid = threadIdx.x;
  const int wave = tid >> 6;
  const int lane = tid & 63;
  const int quad = lane >> 4;
  const int l16 = lane & 15;
  const int colg = (cg << 6) + (wave << 4) + l16;  // this lane's output column

  // B fragments, register-resident: B[k][n], lane elem j <-> k = ki*32+quad*8+j, n = colg
  bf16x8 Bhi[16], Blo[16];
#pragma unroll
  for (int ki = 0; ki < 16; ++ki) {
#pragma unroll
    for (int j = 0; j < 8; ++j) {
      int k = (ki << 5) + (quad << 3) + j;
      float v = Borth[k * HDIM + colg];
      unsigned short hb = f2bf(v);
      unsigned short lb = f2bf(v - bf2f(hb));
      Bhi[ki][j] = __builtin_bit_cast(__bf16, hb);
      Blo[ki][j] = __builtin_bit_cast(__bf16, lb);
    }
  }
  const float win = W_in[colg];
  const float bm = b_mod[colg];

  unsigned* const gbase0 = h0p + (gb << 13);  // rows gb*16..: 8192 contiguous dwords
  unsigned* const gbase1 = h1p + (gb << 13);
  unsigned* const myflag = flags + ((gb << 3) + cg) * 32;  // 128 B apart
  unsigned* const gflags = flags + (gb << 3) * 32;
  const unsigned swz = (unsigned)((l16 & 7) << 2);  // per-lane read swizzle

  for (int t = 0; t < TSTEPS; ++t) {
    const unsigned* __restrict__ cur = (t & 1) ? gbase1 : gbase0;
    unsigned* __restrict__ nxt = (t & 1) ? gbase0 : gbase1;

    // ---- cooperative stage: 4096 qwords; lane tid loads qword tid + 256*i ----
    unsigned long long q[16];
    const unsigned long long* curq = (const unsigned long long*)cur;
#pragma unroll
    for (int i = 0; i < 16; ++i)
      q[i] = __hip_atomic_load(curq + tid + (i << 8), __ATOMIC_RELAXED,
                               __HIP_MEMORY_SCOPE_AGENT);
#pragma unroll
    for (int i = 0; i < 16; ++i) {
      // row = i, logical dword col = 2*tid; swizzled write (b64 stays aligned:
      // XOR touches bits[4:2] only, bit0 preserved)
      unsigned phys = ((unsigned)i << 9) | (((unsigned)(tid << 1)) ^ ((i & 7) << 2));
      *(unsigned long long*)(tileA + phys) = q[i];
    }
    __syncthreads();

    // ---- fragment reads + split-bf16 MFMA ----
    f32x4 a_hh = {0.f, 0.f, 0.f, 0.f};
    f32x4 a_lh = {0.f, 0.f, 0.f, 0.f};
    f32x4 a_hl = {0.f, 0.f, 0.f, 0.f};
#pragma unroll
    for (int ki = 0; ki < 16; ++ki) {
      int c0 = (ki << 5) + (quad << 3);
      // note: (c0+4)^swz != (c0^swz)+4 -- compute both physical addrs
      const unsigned* lp0 = tileA + (l16 << 9) + ((unsigned)c0 ^ swz);
      const unsigned* lp1 = tileA + (l16 << 9) + ((unsigned)(c0 + 4) ^ swz);
      uint4v d0 = *(const uint4v*)lp0;  // j = 0..3 (order preserved within block)
      uint4v d1 = *(const uint4v*)lp1;  // j = 4..7
      unsigned d[8] = {d0[0], d0[1], d0[2], d0[3], d1[0], d1[1], d1[2], d1[3]};
      uint4v vh, vl;
#pragma unroll
      for (int p = 0; p < 4; ++p) {
        vh[p] = __builtin_amdgcn_perm(d[2 * p + 1], d[2 * p], 0x07060302u);
        vl[p] = __builtin_amdgcn_perm(d[2 * p + 1], d[2 * p], 0x05040100u);
      }
      bf16x8 ah = __builtin_bit_cast(bf16x8, vh);
      bf16x8 al = __builtin_bit_cast(bf16x8, vl);
      a_hh = __builtin_amdgcn_mfma_f32_16x16x32_bf16(ah, Bhi[ki], a_hh, 0, 0, 0);
      a_lh = __builtin_amdgcn_mfma_f32_16x16x32_bf16(al, Bhi[ki], a_lh, 0, 0, 0);
      a_hl = __builtin_amdgcn_mfma_f32_16x16x32_bf16(ah, Blo[ki], a_hl, 0, 0, 0);
    }

    // C/D layout: row = quad*4 + r, col = l16  [R3-proven]
    const f32x4 xps = *(const f32x4*)(xp + t * BATCH + (gb << 4) + (quad << 2));
#pragma unroll
    for (int r = 0; r < 4; ++r) {
      float pre = a_hh[r] + a_lh[r] + a_hl[r] + xps[r] * win;
      float mm = fmaxf(fabsf(pre) + bm, 0.f);
      float hv = (pre > 0.f) ? mm : ((pre < 0.f) ? -mm : 0.f);
      int idx = (((quad << 2) + r) << 9) + colg;  // local row * 512 + col
      unsigned short hbv = f2bf(hv);
      unsigned short lbv = f2bf(hv - bf2f(hbv));
      unsigned pk = ((unsigned)hbv << 16) | (unsigned)lbv;
      __hip_atomic_store(nxt + idx, pk, __ATOMIC_RELAXED, __HIP_MEMORY_SCOPE_AGENT);
    }

    // ---- flag barrier (8 WGs per group) ----
    asm volatile("s_waitcnt vmcnt(0)" ::: "memory");  // h stores at coherence point
    __syncthreads();                                  // all 4 waves drained + done reading LDS
    if (tid == 0)
      __hip_atomic_store(myflag, (unsigned)(t + 1), __ATOMIC_RELAXED,
                         __HIP_MEMORY_SCOPE_AGENT);
    const unsigned target = (unsigned)(t + 1);
    int spin = 0;
    for (;;) {
      unsigned fl = __hip_atomic_load(gflags + (lane & 7) * 32, __ATOMIC_RELAXED,
                                      __HIP_MEMORY_SCOPE_AGENT);
      if (__ballot(fl >= target) == ~0ull) break;
      __builtin_amdgcn_s_sleep(1);
      if (++spin > (1 << 22)) break;  // anti-hang valve
    }
  }

  // ---- head: out = hT @ W_lin^T + b_lin ; final h in h0p (t=783 odd -> writes gbase0) ----
  if (cg == 0) {
    int row = tid >> 4;  // 0..15
    int cls = tid & 15;
    if (cls < NCLS) {
      const unsigned* hf = gbase0 + (row << 9);
      float s = b_lin[cls];
      const float* wl = W_lin + cls * HDIM;
      for (int k = 0; k < HDIM; ++k) {
        unsigned p = __hip_atomic_load(hf + k, __ATOMIC_RELAXED, __HIP_MEMORY_SCOPE_AGENT);
        float hvv = bf2f(p >> 16) + bf2f(p & 0xffffu);
        s = fmaf(hvv, wl[k], s);
      }
      out[((gb << 4) + row) * NCLS + cls] = s;
    }
  }
}

extern "C" void kernel_launch(void* const* d_in, const int* in_sizes, int n_in,
                              void* d_out, int out_size, void* d_ws, size_t ws_size,
                              hipStream_t stream) {
  const float* inputs = (const float*)d_in[0];  // 256x784
  const int* perm = (const int*)d_in[1];        // 784 (int64 -> int32 by harness)
  const float* W_skew = (const float*)d_in[2];  // 512x512
  const float* W_in = (const float*)d_in[3];    // 512
  const float* b_mod = (const float*)d_in[4];   // 512
  const float* W_lin = (const float*)d_in[5];   // 10x512
  const float* b_lin = (const float*)d_in[6];   // 10
  float* out = (float*)d_out;

  char* ws = (char*)d_ws;
  unsigned* flags = (unsigned*)ws;           // 128 WGs * 128B = 16KB (32KB reserved)
  unsigned* h0p = (unsigned*)(ws + 32768);   // 128K dwords = 512KB
  unsigned* h1p = h0p + BATCH * HDIM;
  float* xp = (float*)(h1p + BATCH * HDIM);
  float* X = xp + TSTEPS * BATCH;
  float* P = X + HDIM * HDIM;
  float* Q = P + HDIM * HDIM;
  // total ws use ~5.0 MB

  hipMemsetAsync(flags, 0, 32768, stream);
  hipMemsetAsync(h0p, 0, (size_t)BATCH * HDIM * sizeof(unsigned), stream);

  gather_xp<<<TSTEPS, 256, 0, stream>>>(inputs, perm, xp);
  build_X<<<(HDIM * HDIM) / 256, 256, 0, stream>>>(W_skew, X);

  // expm(A) = (T6(A/32))^(2^5)
  axpyI<<<(HDIM * HDIM) / 256, 256, 0, stream>>>(P, X, 1.f / 6.f);
  float* a = P;
  float* b = Q;
  for (int k = 5; k >= 1; --k) {
    gemm512<<<dim3(8, 8), dim3(16, 16), 0, stream>>>(b, X, a, 1.f / (float)k, 1);
    float* tmp = a; a = b; b = tmp;
  }
  for (int i = 0; i < 5; ++i) {
    gemm512<<<dim3(8, 8), dim3(16, 16), 0, stream>>>(b, a, a, 1.f, 0);
    float* tmp = a; a = b; b = tmp;
  }

  rnn_main<<<NGRP * WGPG, 256, 0, stream>>>(xp, a, W_in, b_mod, W_lin, b_lin,
                                            h0p, h1p, flags, out);
  (void)in_sizes; (void)n_in; (void)out_size; (void)ws_size;
}